// Round 11
// baseline (44.245 us; speedup 1.0000x reference)
//
#include <hip/hip_runtime.h>
#include <math.h>

#define NB 32
#define HDIM 512
#define WDIM 512
#define HW (HDIM * WDIM)
#define PSTR 32   // floats per batch param block
#define LIN11_OFF 1024
#define LIN01_OFF 1536
#define NEARD 0.25f

struct __attribute__((packed, aligned(4))) F3 { float x, y, z; };
typedef float f32x2 __attribute__((ext_vector_type(2)));

static __device__ __forceinline__ f32x2 sp(float v) { return (f32x2){v, v}; }

// 3x3 f32 matmul, fma-ascending-k accumulation (matches BLAS sgemm microkernel)
__device__ inline void mm3(float* C, const float* A, const float* B) {
#pragma unroll
  for (int i = 0; i < 3; ++i) {
#pragma unroll
    for (int j = 0; j < 3; ++j) {
      float acc = __fmaf_rn(A[i*3+0], B[0*3+j], 0.0f);
      acc = __fmaf_rn(A[i*3+1], B[1*3+j], acc);
      acc = __fmaf_rn(A[i*3+2], B[2*3+j], acc);
      C[i*3+j] = acc;
    }
  }
}

// 512 threads: fill linspace tables; threads 0..31 also build per-batch params.
__global__ void setup_params(const float* __restrict__ geom,
                             const float* __restrict__ color,
                             const float* __restrict__ cut,
                             float* __restrict__ W) {
  const int t = threadIdx.x;
  W[LIN11_OFF + t] = (float)((double)t * (2.0 / 511.0) + (-1.0));
  W[LIN01_OFF + t] = (float)((double)t * (1.0 / 511.0));
  if (t >= NB) return;
  const int b = t;

  const float DEGf = (float)(3.14159265358979323846 / 180.0);
  const float a15  = 15.0f * DEGf;
  const float a10  = 10.0f * DEGf;

  const float* g = geom + b * 8;
  float tilt = __fmul_rn(__fsub_rn(__fmul_rn(g[1], 2.0f), 1.0f), a15);
  float pan  = __fmul_rn(__fsub_rn(__fmul_rn(g[2], 2.0f), 1.0f), a15);
  float rotf = __fmul_rn(__fsub_rn(__fmul_rn(g[3], 2.0f), 1.0f), a15);
  float sc   = __fadd_rn(1.0f,
                 __fmul_rn(__fsub_rn(__fmul_rn(g[4], 2.0f), 1.0f), 0.1f));
  float tx   = __fmul_rn(__fsub_rn(__fmul_rn(g[5], 2.0f), 1.0f), 0.2f);
  float ty   = __fmul_rn(__fsub_rn(__fmul_rn(g[6], 2.0f), 1.0f), 0.2f);
  float fx   = (g[0] > 0.5f) ? -1.0f : 1.0f;

  float ct = (float)cos((double)tilt), st = (float)sin((double)tilt);
  float cp = (float)cos((double)pan),  sp_ = (float)sin((double)pan);
  float cr = (float)cos((double)rotf), sr = (float)sin((double)rotf);

  float sccr = __fmul_rn(sc, cr);
  float scsr = __fmul_rn(sc, sr);

  float F[9]  = {fx, 0.f, 0.f,  0.f, 1.f, 0.f,  0.f, 0.f, 1.f};
  float Rx[9] = {1.f, 0.f, 0.f,  0.f, ct, -st,  0.f, st, ct};
  float Ry[9] = {cp, 0.f, sp_,  0.f, 1.f, 0.f,  -sp_, 0.f, cp};
  float RS[9] = {sccr, -scsr, 0.f,  scsr, sccr, 0.f,  0.f, 0.f, 1.f};
  float T[9]  = {1.f, 0.f, tx,  0.f, 1.f, ty,  0.f, 0.f, 1.f};

  float t1[9], t2[9], M[9];
  mm3(t1, T, RS);
  mm3(t2, t1, Rx);
  mm3(t1, t2, Ry);
  mm3(M, t1, F);

  const float* c = color + b * 4;
  float theta  = __fmul_rn(__fsub_rn(__fmul_rn(c[0], 2.0f), 1.0f), a10);
  float sat    = __fadd_rn(1.0f,
                   __fmul_rn(__fsub_rn(__fmul_rn(c[1], 2.0f), 1.0f), 0.4f));
  float bright = __fadd_rn(1.0f,
                   __fmul_rn(__fsub_rn(__fmul_rn(c[2], 2.0f), 1.0f), 0.1f));
  float gammaf = __fadd_rn(1.0f,
                   __fmul_rn(__fsub_rn(__fmul_rn(c[3], 2.0f), 1.0f), 0.2f));

  float cth = (float)cos((double)theta), sth = (float)sin((double)theta);
  float omc = __fsub_rn(1.0f, cth);
  float oms = __fsub_rn(1.0f, sat);
  const float aK = (float)(1.0 / sqrt(3.0));
  const float Af = (float)(1.0 / 3.0);
  const float K[9]   = {0.f, -aK, aK,  aK, 0.f, -aK,  -aK, aK, 0.f};
  const float lum[3] = {(float)0.299, (float)0.587, (float)0.114};

  float Rh[9], Sm[9], SR[9];
#pragma unroll
  for (int i = 0; i < 3; ++i) {
#pragma unroll
    for (int j = 0; j < 3; ++j) {
      float I = (i == j) ? 1.0f : 0.0f;
      Rh[i*3+j] = __fadd_rn(
          __fadd_rn(__fmul_rn(cth, I), __fmul_rn(sth, K[i*3+j])),
          __fmul_rn(omc, Af));
      Sm[i*3+j] = __fadd_rn(__fmul_rn(sat, I), __fmul_rn(oms, lum[j]));
    }
  }
  mm3(SR, Sm, Rh);

  float* pp = W + b * PSTR;
#pragma unroll
  for (int i = 0; i < 9; ++i) pp[i] = M[i];
#pragma unroll
  for (int i = 0; i < 9; ++i) pp[9 + i] = __fmul_rn(bright, SR[i]);
  pp[18] = gammaf;

  const float* cu = cut + b * 5;
  pp[19] = (cu[0] < 0.5f) ? 1.0f : 0.0f;
  pp[20] = cu[1];
  pp[21] = cu[2];
  pp[22] = __fmul_rn(__fadd_rn(0.3f, __fmul_rn(0.2f, cu[3])), 0.5f);
  pp[23] = __fmul_rn(__fadd_rn(0.3f, __fmul_rn(0.2f, cu[4])), 0.5f);
}

// 512-thread blocks, 32x64 tile; thread t owns a 4-pixel COLUMN.
// A-phase: packed f32x2 over pixel pairs, fast shared reciprocal with exact
// __fdiv_rn fallback within NEARD of the valid-mask boundary (the only
// discontinuity). C-phase: packed f32x2 over channel/output pairs.
__global__ __launch_bounds__(512, 1) void augment_kernel(
    const float* __restrict__ img, const float* __restrict__ W,
    float* __restrict__ out) {
  // XCD swizzle: each XCD walks batches contiguously (3.1 MB image streams
  // through its private 4 MB L2). 4096 % 8 == 0 -> bijective.
  const int bkid = ((blockIdx.x & 7) << 9) | ((int)blockIdx.x >> 3);
  const int bb = bkid >> 7;                       // 128 tiles per batch
  const int tile = bkid & 127;
  const int t = (int)threadIdx.x;
  const int xx  = ((tile & 15) << 5) | (t & 31);        // 0..511
  const int yy0 = ((tile >> 4) << 6) | ((t >> 5) << 2); // 0..508, step 4

  const float* pp = W + bb * PSTR;
  const float m00 = pp[0], m01 = pp[1], m02 = pp[2];
  const float m10 = pp[3], m11 = pp[4], m12 = pp[5];
  const float m20 = pp[6], m21 = pp[7], m22 = pp[8];

  const float xs = W[LIN11_OFF + xx];
  const float4 ysv = *(const float4*)(W + LIN11_OFF + yy0);

  // hoisted x-products (same IEEE products as reference, computed once)
  const float m00xs = __fmul_rn(m00, xs);
  const float m10xs = __fmul_rn(m10, xs);
  const float m20xs = __fmul_rn(m20, xs);

  // ---- Phase A: packed projective transform, 2 pixel-pairs ----
  float pxa[4], pya[4];
  {
    const f32x2 vm01 = sp(m01), vm11 = sp(m11), vm21 = sp(m21);
    const f32x2 vm02 = sp(m02), vm12 = sp(m12), vm22 = sp(m22);
    const f32x2 vm00xs = sp(m00xs), vm10xs = sp(m10xs), vm20xs = sp(m20xs);
#pragma unroll
    for (int p = 0; p < 2; ++p) {
      const f32x2 ys = p ? (f32x2){ysv.z, ysv.w} : (f32x2){ysv.x, ysv.y};
      f32x2 s0, s1, s2;
      {
#pragma clang fp contract(off)
        s0 = (vm00xs + vm01 * ys) + vm02;
        s1 = (vm10xs + vm11 * ys) + vm12;
        s2 = (vm20xs + vm21 * ys) + vm22;
      }
      // fast reciprocal + 1 NR step, shared by u and v
      f32x2 r = {__builtin_amdgcn_rcpf(s2.x), __builtin_amdgcn_rcpf(s2.y)};
      const f32x2 e = __builtin_elementwise_fma(-s2, r, sp(1.0f));
      r = __builtin_elementwise_fma(e, r, r);
      f32x2 px2, py2;
      {
#pragma clang fp contract(off)
        const f32x2 u = s0 * r;
        const f32x2 v = s1 * r;
        px2 = ((u + sp(1.0f)) * sp(0.5f)) * sp(511.0f);
        py2 = ((v + sp(1.0f)) * sp(0.5f)) * sp(511.0f);
      }
#pragma unroll
      for (int h = 0; h < 2; ++h) {
        const int i = p * 2 + h;
        float px = h ? px2.y : px2.x;
        float py = h ? py2.y : py2.x;
        // Fast px/py error <= ~1e-4 px. Only the valid mask is discontinuous:
        // within NEARD of its boundary, redo with the exact reference chain.
        const bool nearb =
            (fabsf(px) < NEARD) || (fabsf(px - 511.0f) < NEARD) ||
            (fabsf(py) < NEARD) || (fabsf(py - 511.0f) < NEARD);
        if (nearb) {
          const float S0 = h ? s0.y : s0.x;
          const float S1 = h ? s1.y : s1.x;
          const float S2 = h ? s2.y : s2.x;
          const float ue = __fdiv_rn(S0, S2);
          const float ve = __fdiv_rn(S1, S2);
          px = __fmul_rn(__fmul_rn(__fadd_rn(ue, 1.0f), 0.5f), 511.0f);
          py = __fmul_rn(__fmul_rn(__fadd_rn(ve, 1.0f), 0.5f), 511.0f);
        }
        pxa[i] = px;
        pya[i] = py;
      }
    }
  }

  float wxa[4], wya[4], vma[4];
  int o00[4], o01[4], o10[4], o11[4];
#pragma unroll
  for (int i = 0; i < 4; ++i) {
    const float px = pxa[i], py = pya[i];
    vma[i] =
        (px >= 0.0f && px <= 511.0f && py >= 0.0f && py <= 511.0f) ? 1.0f
                                                                   : 0.0f;
    const float pxc = __builtin_amdgcn_fmed3f(px, 0.0f, 511.0f);
    const float pyc = __builtin_amdgcn_fmed3f(py, 0.0f, 511.0f);
    const float x0f = floorf(pxc), y0f = floorf(pyc);
    wxa[i] = pxc - x0f;
    wya[i] = pyc - y0f;
    const int x0 = (int)x0f, y0 = (int)y0f;
    const int o = (y0 * WDIM + x0) * 3;
    const int dx = (x0 < WDIM - 1) ? 3 : 0;
    const int dy = (y0 < HDIM - 1) ? WDIM * 3 : 0;
    o00[i] = o;
    o01[i] = o + dx;
    o10[i] = o + dy;
    o11[i] = o + dy + dx;
  }

  // ---- Phase B: issue all 16 gather loads (dwordx3 each) ----
  const float* base = img + (size_t)bb * (HW * 3);
  F3 g00[4], g01[4], g10[4], g11[4];
#pragma unroll
  for (int i = 0; i < 4; ++i) {
    g00[i] = *(const F3*)(base + o00[i]);
    g01[i] = *(const F3*)(base + o01[i]);
    g10[i] = *(const F3*)(base + o10[i]);
    g11[i] = *(const F3*)(base + o11[i]);
  }
  __builtin_amdgcn_sched_barrier(0);

  // ---- Phase C: bilinear + gamma + color + cutout (channel-packed) ----
  const f32x2 cA = {pp[9], pp[12]};   // Mc[0][0], Mc[1][0]
  const f32x2 cB = {pp[10], pp[13]};  // Mc[0][1], Mc[1][1]
  const f32x2 cC = {pp[11], pp[14]};  // Mc[0][2], Mc[1][2]
  const float c20 = pp[15], c21 = pp[16], c22 = pp[17];
  const float gamma = pp[18];
  const float capply = pp[19], ccx = pp[20], ccy = pp[21];
  const float chw = pp[22], chh = pp[23];

  const float gx = W[LIN01_OFF + xx];
  const float4 gyv = *(const float4*)(W + LIN01_OFF + yy0);
  const float gya[4] = {gyv.x, gyv.y, gyv.z, gyv.w};
  const bool cutx = (capply != 0.0f) && (fabsf(__fsub_rn(gx, ccx)) < chw);

  const size_t pix0 = (size_t)bb * HW + (size_t)yy0 * WDIM + xx;
#pragma unroll
  for (int i = 0; i < 4; ++i) {
    const float wx = wxa[i], wy = wya[i], vm = vma[i];
    const float ax = (1.0f - wx) * vm;
    const float bx = wx * vm;
    const float omwy = 1.0f - wy;
    const float w00 = ax * omwy, w01 = bx * omwy;
    const float w10 = ax * wy,   w11 = bx * wy;

    const f32x2 gxy00 = {g00[i].x, g00[i].y};
    const f32x2 gxy01 = {g01[i].x, g01[i].y};
    const f32x2 gxy10 = {g10[i].x, g10[i].y};
    const f32x2 gxy11 = {g11[i].x, g11[i].y};
    f32x2 sxy =
        gxy00 * sp(w00) + gxy01 * sp(w01) + gxy10 * sp(w10) + gxy11 * sp(w11);
    float sz = g00[i].z * w00 + g01[i].z * w01 + g10[i].z * w10 + g11[i].z * w11;

    const float sx = __builtin_amdgcn_fmed3f(sxy.x, 0.0f, 1.0f);
    const float sy = __builtin_amdgcn_fmed3f(sxy.y, 0.0f, 1.0f);
    sz = __builtin_amdgcn_fmed3f(sz, 0.0f, 1.0f);
    const float r0 = __builtin_amdgcn_exp2f(gamma * __builtin_amdgcn_logf(sx));
    const float r1 = __builtin_amdgcn_exp2f(gamma * __builtin_amdgcn_logf(sy));
    const float r2 = __builtin_amdgcn_exp2f(gamma * __builtin_amdgcn_logf(sz));

    f32x2 q01 = cA * sp(r0) + cB * sp(r1) + cC * sp(r2);
    float q2v = c20 * r0 + c21 * r1 + c22 * r2;
    float q0 = __builtin_amdgcn_fmed3f(q01.x, 0.0f, 1.0f);
    float q1 = __builtin_amdgcn_fmed3f(q01.y, 0.0f, 1.0f);
    float q2 = __builtin_amdgcn_fmed3f(q2v, 0.0f, 1.0f);

    const bool cutm = cutx && (fabsf(__fsub_rn(gya[i], ccy)) < chh);
    if (cutm) { q0 = 0.0f; q1 = 0.0f; q2 = 0.0f; }

    F3 o; o.x = q0; o.y = q1; o.z = q2;
    *(F3*)(out + (pix0 + (size_t)i * WDIM) * 3) = o;
  }
}

extern "C" void kernel_launch(void* const* d_in, const int* in_sizes, int n_in,
                              void* d_out, int out_size, void* d_ws, size_t ws_size,
                              hipStream_t stream) {
  const float* images = (const float*)d_in[0];
  const float* geom   = (const float*)d_in[1];
  const float* color  = (const float*)d_in[2];
  const float* cutu   = (const float*)d_in[3];
  float* W = (float*)d_ws;   // 2048 floats = 8 KB scratch

  setup_params<<<1, 512, 0, stream>>>(geom, color, cutu, W);

  const int npix = NB * HW;
  augment_kernel<<<npix / 2048, 512, 0, stream>>>(images, W, (float*)d_out);
}

// Round 12
// 39.724 us; speedup vs baseline: 1.1138x; 1.1138x over previous
//
#include <hip/hip_runtime.h>
#include <math.h>

#define NB 32
#define HDIM 512
#define WDIM 512
#define HW (HDIM * WDIM)
#define PSTR 32   // floats per batch param block
#define LIN11_OFF 1024
#define LIN01_OFF 1536

struct __attribute__((packed, aligned(4))) F3 { float x, y, z; };
struct PixA { float wx, wy, vm; int o00, o01, o10, o11; };

// 3x3 f32 matmul, fma-ascending-k accumulation (matches BLAS sgemm microkernel)
__device__ inline void mm3(float* C, const float* A, const float* B) {
#pragma unroll
  for (int i = 0; i < 3; ++i) {
#pragma unroll
    for (int j = 0; j < 3; ++j) {
      float acc = __fmaf_rn(A[i*3+0], B[0*3+j], 0.0f);
      acc = __fmaf_rn(A[i*3+1], B[1*3+j], acc);
      acc = __fmaf_rn(A[i*3+2], B[2*3+j], acc);
      C[i*3+j] = acc;
    }
  }
}

// 512 threads: fill linspace tables; threads 0..31 also build per-batch params.
__global__ void setup_params(const float* __restrict__ geom,
                             const float* __restrict__ color,
                             const float* __restrict__ cut,
                             float* __restrict__ W) {
  const int t = threadIdx.x;
  W[LIN11_OFF + t] = (float)((double)t * (2.0 / 511.0) + (-1.0));
  W[LIN01_OFF + t] = (float)((double)t * (1.0 / 511.0));
  if (t >= NB) return;
  const int b = t;

  const float DEGf = (float)(3.14159265358979323846 / 180.0);
  const float a15  = 15.0f * DEGf;
  const float a10  = 10.0f * DEGf;

  const float* g = geom + b * 8;
  float tilt = __fmul_rn(__fsub_rn(__fmul_rn(g[1], 2.0f), 1.0f), a15);
  float pan  = __fmul_rn(__fsub_rn(__fmul_rn(g[2], 2.0f), 1.0f), a15);
  float rotf = __fmul_rn(__fsub_rn(__fmul_rn(g[3], 2.0f), 1.0f), a15);
  float sc   = __fadd_rn(1.0f,
                 __fmul_rn(__fsub_rn(__fmul_rn(g[4], 2.0f), 1.0f), 0.1f));
  float tx   = __fmul_rn(__fsub_rn(__fmul_rn(g[5], 2.0f), 1.0f), 0.2f);
  float ty   = __fmul_rn(__fsub_rn(__fmul_rn(g[6], 2.0f), 1.0f), 0.2f);
  float fx   = (g[0] > 0.5f) ? -1.0f : 1.0f;

  float ct = (float)cos((double)tilt), st = (float)sin((double)tilt);
  float cp = (float)cos((double)pan),  sp = (float)sin((double)pan);
  float cr = (float)cos((double)rotf), sr = (float)sin((double)rotf);

  float sccr = __fmul_rn(sc, cr);
  float scsr = __fmul_rn(sc, sr);

  float F[9]  = {fx, 0.f, 0.f,  0.f, 1.f, 0.f,  0.f, 0.f, 1.f};
  float Rx[9] = {1.f, 0.f, 0.f,  0.f, ct, -st,  0.f, st, ct};
  float Ry[9] = {cp, 0.f, sp,  0.f, 1.f, 0.f,  -sp, 0.f, cp};
  float RS[9] = {sccr, -scsr, 0.f,  scsr, sccr, 0.f,  0.f, 0.f, 1.f};
  float T[9]  = {1.f, 0.f, tx,  0.f, 1.f, ty,  0.f, 0.f, 1.f};

  float t1[9], t2[9], M[9];
  mm3(t1, T, RS);
  mm3(t2, t1, Rx);
  mm3(t1, t2, Ry);
  mm3(M, t1, F);

  const float* c = color + b * 4;
  float theta  = __fmul_rn(__fsub_rn(__fmul_rn(c[0], 2.0f), 1.0f), a10);
  float sat    = __fadd_rn(1.0f,
                   __fmul_rn(__fsub_rn(__fmul_rn(c[1], 2.0f), 1.0f), 0.4f));
  float bright = __fadd_rn(1.0f,
                   __fmul_rn(__fsub_rn(__fmul_rn(c[2], 2.0f), 1.0f), 0.1f));
  float gammaf = __fadd_rn(1.0f,
                   __fmul_rn(__fsub_rn(__fmul_rn(c[3], 2.0f), 1.0f), 0.2f));

  float cth = (float)cos((double)theta), sth = (float)sin((double)theta);
  float omc = __fsub_rn(1.0f, cth);
  float oms = __fsub_rn(1.0f, sat);
  const float aK = (float)(1.0 / sqrt(3.0));
  const float Af = (float)(1.0 / 3.0);
  const float K[9]   = {0.f, -aK, aK,  aK, 0.f, -aK,  -aK, aK, 0.f};
  const float lum[3] = {(float)0.299, (float)0.587, (float)0.114};

  float Rh[9], Sm[9], SR[9];
#pragma unroll
  for (int i = 0; i < 3; ++i) {
#pragma unroll
    for (int j = 0; j < 3; ++j) {
      float I = (i == j) ? 1.0f : 0.0f;
      Rh[i*3+j] = __fadd_rn(
          __fadd_rn(__fmul_rn(cth, I), __fmul_rn(sth, K[i*3+j])),
          __fmul_rn(omc, Af));
      Sm[i*3+j] = __fadd_rn(__fmul_rn(sat, I), __fmul_rn(oms, lum[j]));
    }
  }
  mm3(SR, Sm, Rh);

  float* pp = W + b * PSTR;
#pragma unroll
  for (int i = 0; i < 9; ++i) pp[i] = M[i];
#pragma unroll
  for (int i = 0; i < 9; ++i) pp[9 + i] = __fmul_rn(bright, SR[i]);
  pp[18] = gammaf;

  const float* cu = cut + b * 5;
  pp[19] = (cu[0] < 0.5f) ? 1.0f : 0.0f;
  pp[20] = cu[1];
  pp[21] = cu[2];
  pp[22] = __fmul_rn(__fadd_rn(0.3f, __fmul_rn(0.2f, cu[3])), 0.5f);
  pp[23] = __fmul_rn(__fadd_rn(0.3f, __fmul_rn(0.2f, cu[4])), 0.5f);
}

// 128-thread blocks (2 waves/WG; 16-WG/CU slot limit -> up to 32 waves/CU).
// 32x16 pixel tile per block; thread t owns a 4-pixel COLUMN:
//   x = tile_x*32 + (t&31), rows = tile_y*16 + (t>>5)*4 .. +3.
// Two-stage software pipeline: A(0,1) B(0,1) | A(2,3) B(2,3) | C(0..3).
__global__ __launch_bounds__(128, 1) void augment_kernel(
    const float* __restrict__ img, const float* __restrict__ W,
    float* __restrict__ out) {
  // XCD swizzle: each XCD walks batches contiguously (3.1 MB image streams
  // through its private 4 MB L2). 16384 % 8 == 0 -> bijective.
  const int bkid = ((blockIdx.x & 7) << 11) | ((int)blockIdx.x >> 3);
  const int bb = bkid >> 9;                       // 512 tiles per batch
  const int tile = bkid & 511;
  const int t = (int)threadIdx.x;
  const int xx  = ((tile & 15) << 5) | (t & 31);        // 0..511
  const int yy0 = ((tile >> 4) << 4) | ((t >> 5) << 2); // 0..508, step 4

  const float* pp = W + bb * PSTR;
  const float m00 = pp[0], m01 = pp[1], m02 = pp[2];
  const float m10 = pp[3], m11 = pp[4], m12 = pp[5];
  const float m20 = pp[6], m21 = pp[7], m22 = pp[8];

  const float xs = W[LIN11_OFF + xx];
  const float4 ysv = *(const float4*)(W + LIN11_OFF + yy0);
  const float ysa[4] = {ysv.x, ysv.y, ysv.z, ysv.w};

  // hoisted x-products (same IEEE products as reference, computed once)
  const float m00xs = __fmul_rn(m00, xs);
  const float m10xs = __fmul_rn(m10, xs);
  const float m20xs = __fmul_rn(m20, xs);

  const float* base = img + (size_t)bb * (HW * 3);

  auto A = [&](float ys) -> PixA {
    PixA r;
    const float s0 = __fadd_rn(__fadd_rn(m00xs, __fmul_rn(m01, ys)), m02);
    const float s1 = __fadd_rn(__fadd_rn(m10xs, __fmul_rn(m11, ys)), m12);
    const float s2 = __fadd_rn(__fadd_rn(m20xs, __fmul_rn(m21, ys)), m22);
    const float u = __fdiv_rn(s0, s2);
    const float v = __fdiv_rn(s1, s2);
    const float px = __fmul_rn(__fmul_rn(__fadd_rn(u, 1.0f), 0.5f), 511.0f);
    const float py = __fmul_rn(__fmul_rn(__fadd_rn(v, 1.0f), 0.5f), 511.0f);
    r.vm = (px >= 0.0f && px <= 511.0f && py >= 0.0f && py <= 511.0f) ? 1.0f
                                                                      : 0.0f;
    const float pxc = __builtin_amdgcn_fmed3f(px, 0.0f, 511.0f);
    const float pyc = __builtin_amdgcn_fmed3f(py, 0.0f, 511.0f);
    const float x0f = floorf(pxc), y0f = floorf(pyc);
    r.wx = pxc - x0f;
    r.wy = pyc - y0f;
    const int x0 = (int)x0f, y0 = (int)y0f;
    const int o = (y0 * WDIM + x0) * 3;
    const int dx = (x0 < WDIM - 1) ? 3 : 0;
    const int dy = (y0 < HDIM - 1) ? WDIM * 3 : 0;
    r.o00 = o;
    r.o01 = o + dx;
    r.o10 = o + dy;
    r.o11 = o + dy + dx;
    return r;
  };

  // ---- Stage 1: A + issue loads for pixels 0,1 ----
  PixA a0 = A(ysa[0]);
  PixA a1 = A(ysa[1]);
  F3 g00_0 = *(const F3*)(base + a0.o00);
  F3 g01_0 = *(const F3*)(base + a0.o01);
  F3 g10_0 = *(const F3*)(base + a0.o10);
  F3 g11_0 = *(const F3*)(base + a0.o11);
  F3 g00_1 = *(const F3*)(base + a1.o00);
  F3 g01_1 = *(const F3*)(base + a1.o01);
  F3 g10_1 = *(const F3*)(base + a1.o10);
  F3 g11_1 = *(const F3*)(base + a1.o11);
  __builtin_amdgcn_sched_barrier(0);

  // ---- Stage 2: A + issue loads for pixels 2,3 (hides stage-1 latency) ----
  PixA a2 = A(ysa[2]);
  PixA a3 = A(ysa[3]);
  F3 g00_2 = *(const F3*)(base + a2.o00);
  F3 g01_2 = *(const F3*)(base + a2.o01);
  F3 g10_2 = *(const F3*)(base + a2.o10);
  F3 g11_2 = *(const F3*)(base + a2.o11);
  F3 g00_3 = *(const F3*)(base + a3.o00);
  F3 g01_3 = *(const F3*)(base + a3.o01);
  F3 g10_3 = *(const F3*)(base + a3.o10);
  F3 g11_3 = *(const F3*)(base + a3.o11);
  __builtin_amdgcn_sched_barrier(0);

  // ---- Consume ----
  const float c00 = pp[9],  c01 = pp[10], c02 = pp[11];
  const float c10 = pp[12], c11 = pp[13], c12 = pp[14];
  const float c20 = pp[15], c21 = pp[16], c22 = pp[17];
  const float gamma = pp[18];
  const float capply = pp[19], ccx = pp[20], ccy = pp[21];
  const float chw = pp[22], chh = pp[23];

  const float gx = W[LIN01_OFF + xx];
  const float4 gyv = *(const float4*)(W + LIN01_OFF + yy0);
  const float gya[4] = {gyv.x, gyv.y, gyv.z, gyv.w};
  const bool cutx = (capply != 0.0f) && (fabsf(__fsub_rn(gx, ccx)) < chw);

  const size_t pix0 = (size_t)bb * HW + (size_t)yy0 * WDIM + xx;

  auto C = [&](const PixA& a, F3 G00, F3 G01, F3 G10, F3 G11, float gy,
               int row) {
    const float ax = (1.0f - a.wx) * a.vm;
    const float bx = a.wx * a.vm;
    const float omwy = 1.0f - a.wy;
    const float w00 = ax * omwy;
    const float w01 = bx * omwy;
    const float w10 = ax * a.wy;
    const float w11 = bx * a.wy;

    float s, r0, r1, r2;
    s = G00.x * w00 + G01.x * w01 + G10.x * w10 + G11.x * w11;
    s = __builtin_amdgcn_fmed3f(s, 0.0f, 1.0f);
    r0 = __builtin_amdgcn_exp2f(gamma * __builtin_amdgcn_logf(s));
    s = G00.y * w00 + G01.y * w01 + G10.y * w10 + G11.y * w11;
    s = __builtin_amdgcn_fmed3f(s, 0.0f, 1.0f);
    r1 = __builtin_amdgcn_exp2f(gamma * __builtin_amdgcn_logf(s));
    s = G00.z * w00 + G01.z * w01 + G10.z * w10 + G11.z * w11;
    s = __builtin_amdgcn_fmed3f(s, 0.0f, 1.0f);
    r2 = __builtin_amdgcn_exp2f(gamma * __builtin_amdgcn_logf(s));

    float q0 = __builtin_amdgcn_fmed3f(c00 * r0 + c01 * r1 + c02 * r2, 0.0f, 1.0f);
    float q1 = __builtin_amdgcn_fmed3f(c10 * r0 + c11 * r1 + c12 * r2, 0.0f, 1.0f);
    float q2 = __builtin_amdgcn_fmed3f(c20 * r0 + c21 * r1 + c22 * r2, 0.0f, 1.0f);

    const bool cutm = cutx && (fabsf(__fsub_rn(gy, ccy)) < chh);
    if (cutm) { q0 = 0.0f; q1 = 0.0f; q2 = 0.0f; }

    F3 o; o.x = q0; o.y = q1; o.z = q2;
    *(F3*)(out + (pix0 + (size_t)row * WDIM) * 3) = o;
  };

  C(a0, g00_0, g01_0, g10_0, g11_0, gya[0], 0);
  C(a1, g00_1, g01_1, g10_1, g11_1, gya[1], 1);
  C(a2, g00_2, g01_2, g10_2, g11_2, gya[2], 2);
  C(a3, g00_3, g01_3, g10_3, g11_3, gya[3], 3);
}

extern "C" void kernel_launch(void* const* d_in, const int* in_sizes, int n_in,
                              void* d_out, int out_size, void* d_ws, size_t ws_size,
                              hipStream_t stream) {
  const float* images = (const float*)d_in[0];
  const float* geom   = (const float*)d_in[1];
  const float* color  = (const float*)d_in[2];
  const float* cutu   = (const float*)d_in[3];
  float* W = (float*)d_ws;   // 2048 floats = 8 KB scratch

  setup_params<<<1, 512, 0, stream>>>(geom, color, cutu, W);

  const int npix = NB * HW;
  augment_kernel<<<npix / 512, 128, 0, stream>>>(images, W, (float*)d_out);
}